// Round 2
// baseline (225.059 us; speedup 1.0000x reference)
//
#include <hip/hip_runtime.h>

// DCT_18769007084406: RGB->YCbCr (1x1 conv) -> 8x8 stride-8 block DCT
// (grouped conv) -> 32x repeated (t-min)/d normalization (closed form).
//
// R4: u-split + non-temporal stores. R3 (one thread = one full 8x8 block)
// was latency-bound: 64 live accumulators forced a 64-VGPR allocation with
// ~1 row of loads in flight, VALUBusy 18%, occupancy 31%.
// Now one wave-task = (batch, block-row band, channel, u-half): each lane
// computes 4 of the 8 DCT output rows of its 8x8 block -> 32 accumulators.
// 12288 wave-tasks, 4 waves per 256-thread workgroup, launch_bounds(256,5)
// caps VGPR at ~102 -> ~20 resident waves/CU. The two u-half waves of the
// same block re-read identical rows -> same CU, L1/MSHR dedup.
// Output stores are non-temporal: output is write-once, keeping it out of
// L2/L3 lets the 100 MB input stay L3-resident across iterations.
// Streaming formulation: out[u][v] = sum_i basis[u][i] * z_i[v],
// z_i[v] = row-DCT of row i -- accumulated per row, so only z[8] + acc[4][8]
// are live, and the compiler can pipeline the next row's 6 loads.

#define HW 512
#define CHST (HW * HW)       // channel stride in x
#define NPAIR 6144           // 32 * 192 (b, out-channel) pairs
#define EPS 1e-6f

// basis[u][i] = c(u) * cos(pi*u*(i+0.5)/8); c(0)=sqrt(1/8), c(u>0)=0.5
static constexpr float BASIS[8][8] = {
  { 0.35355339059327373f, 0.35355339059327373f, 0.35355339059327373f, 0.35355339059327373f,
    0.35355339059327373f, 0.35355339059327373f, 0.35355339059327373f, 0.35355339059327373f },
  { 0.49039264020161522f, 0.41573480615127262f, 0.27778511650980114f, 0.09754516100806412f,
   -0.09754516100806412f,-0.27778511650980114f,-0.41573480615127262f,-0.49039264020161522f },
  { 0.46193976625564337f, 0.19134171618254492f,-0.19134171618254492f,-0.46193976625564337f,
   -0.46193976625564337f,-0.19134171618254492f, 0.19134171618254492f, 0.46193976625564337f },
  { 0.41573480615127262f,-0.09754516100806412f,-0.49039264020161522f,-0.27778511650980114f,
    0.27778511650980114f, 0.49039264020161522f, 0.09754516100806412f,-0.41573480615127262f },
  { 0.35355339059327373f,-0.35355339059327373f,-0.35355339059327373f, 0.35355339059327373f,
    0.35355339059327373f,-0.35355339059327373f,-0.35355339059327373f, 0.35355339059327373f },
  { 0.27778511650980114f,-0.49039264020161522f, 0.09754516100806412f, 0.41573480615127262f,
   -0.41573480615127262f,-0.09754516100806412f, 0.49039264020161522f,-0.27778511650980114f },
  { 0.19134171618254492f,-0.46193976625564337f, 0.46193976625564337f,-0.19134171618254492f,
   -0.19134171618254492f, 0.46193976625564337f,-0.46193976625564337f, 0.19134171618254492f },
  { 0.09754516100806412f,-0.27778511650980114f, 0.41573480615127262f,-0.49039264020161522f,
    0.49039264020161522f,-0.41573480615127262f, 0.27778511650980114f,-0.09754516100806412f }
};

// t_32 = a^32 * t0 - min * sum_{k=1..32} a^k, a = 1/(max-min+eps)
__global__ void precomp_norm(const float* __restrict__ max_,
                             const float* __restrict__ min_,
                             float* __restrict__ so) {
    int i = blockIdx.x * 256 + threadIdx.x;
    if (i >= NPAIR) return;
    float mn = min_[i], mx = max_[i];
    float d = mx - mn + EPS;
    float a = 1.0f / d;
    float a2 = a * a, a4 = a2 * a2, a8 = a4 * a4, a16 = a8 * a8, a32 = a16 * a16;
    float geo = a * (1.0f - a32) / (1.0f - a);   // sum_{k=1..32} a^k
    so[2 * i]     = a32;
    so[2 * i + 1] = -mn * geo;
}

template <bool USE_WS>
__global__ __launch_bounds__(256, 5)
void dct_kernel(const float* __restrict__ x,
                const float* __restrict__ ycbcr_w,
                const float* __restrict__ so,
                const float* __restrict__ max_,
                const float* __restrict__ min_,
                float* __restrict__ out) {
    // wave-task id: ((b*64 + by)*3 + c)*2 + uhalf, 12288 total
    const int wt   = blockIdx.x * 4 + (threadIdx.x >> 6);
    const int bx   = threadIdx.x & 63;       // lane = block-col -> coalesced
    const int band = wt / 6;                 // (b, by)
    const int rem  = wt - band * 6;
    const int c    = rem >> 1;               // YCbCr channel
    const int uh   = (rem & 1) * 4;          // u-half base (0 or 4)
    const int by   = band & 63;
    const int b    = band >> 6;

    // channel weights (wave-uniform)
    const float wr = ycbcr_w[3 * c];
    const float wg = ycbcr_w[3 * c + 1];
    const float wb = ycbcr_w[3 * c + 2];

    // this lane's 8x8 block: rows i at base + i*HW, cols [0,8)
    const float* base = x + (size_t)(b * 3) * CHST + (size_t)(by * 8) * HW + bx * 8;

    float acc[4][8];   // acc[u0][v] = sum_i basis[uh+u0][i] * z_i[v]
#pragma unroll
    for (int u0 = 0; u0 < 4; ++u0)
#pragma unroll
        for (int v = 0; v < 8; ++v) acc[u0][v] = 0.0f;

#pragma unroll
    for (int i = 0; i < 8; ++i) {
        const float* rp = base + i * HW;
        // lane bx reads 32B at bx*32 -> wave covers a contiguous 2KB row
        float4 r0 = *(const float4*)(rp);
        float4 r1 = *(const float4*)(rp + 4);
        float4 g0 = *(const float4*)(rp + CHST);
        float4 g1 = *(const float4*)(rp + CHST + 4);
        float4 b0 = *(const float4*)(rp + 2 * CHST);
        float4 b1 = *(const float4*)(rp + 2 * CHST + 4);

        float y[8];
        y[0] = fmaf(wr, r0.x, fmaf(wg, g0.x, wb * b0.x));
        y[1] = fmaf(wr, r0.y, fmaf(wg, g0.y, wb * b0.y));
        y[2] = fmaf(wr, r0.z, fmaf(wg, g0.z, wb * b0.z));
        y[3] = fmaf(wr, r0.w, fmaf(wg, g0.w, wb * b0.w));
        y[4] = fmaf(wr, r1.x, fmaf(wg, g1.x, wb * b1.x));
        y[5] = fmaf(wr, r1.y, fmaf(wg, g1.y, wb * b1.y));
        y[6] = fmaf(wr, r1.z, fmaf(wg, g1.z, wb * b1.z));
        y[7] = fmaf(wr, r1.w, fmaf(wg, g1.w, wb * b1.w));

        // row DCT: z[v] = sum_j basis[v][j] * y[j]
        float z[8];
#pragma unroll
        for (int v = 0; v < 8; ++v) {
            float zz = y[0] * BASIS[v][0];
#pragma unroll
            for (int j = 1; j < 8; ++j)
                zz = fmaf(y[j], BASIS[v][j], zz);
            z[v] = zz;
        }

        // column accumulate for this thread's 4 u rows
#pragma unroll
        for (int u0 = 0; u0 < 4; ++u0) {
            const float bu = BASIS[uh + u0][i];   // wave-uniform scalar load
#pragma unroll
            for (int v = 0; v < 8; ++v)
                acc[u0][v] = fmaf(bu, z[v], acc[u0][v]);
        }
    }

    const int obase = b * 192 + c * 64;    // first output channel index
    float* op = out + ((size_t)obase * 64 + by) * 64 + bx;
    const float2* sop = (const float2*)so + obase;   // (scale, offset) pairs

#pragma unroll
    for (int u0 = 0; u0 < 4; ++u0) {
#pragma unroll
        for (int v = 0; v < 8; ++v) {
            const int k = (uh + u0) * 8 + v;
            float s, o;
            if (USE_WS) {
                float2 p = sop[k];                 // wave-uniform, L1-hit
                s = p.x;
                o = p.y;
            } else {
                float mn = min_[obase + k], mx = max_[obase + k];
                float d  = mx - mn + EPS;
                float a  = 1.0f / d;
                float a2 = a * a, a4 = a2 * a2, a8 = a4 * a4, a16 = a8 * a8, a32 = a16 * a16;
                s = a32;
                o = -mn * (a * (1.0f - a32) / (1.0f - a));
            }
            // write-once output: keep it out of L2/L3 so input stays resident
            __builtin_nontemporal_store(fmaf(s, acc[u0][v], o),
                                        op + (size_t)k * 4096);
        }
    }
}

extern "C" void kernel_launch(void* const* d_in, const int* in_sizes, int n_in,
                              void* d_out, int out_size, void* d_ws, size_t ws_size,
                              hipStream_t stream) {
    const float* x    = (const float*)d_in[0];
    const float* max_ = (const float*)d_in[1];
    const float* min_ = (const float*)d_in[2];
    const float* yw   = (const float*)d_in[3];
    float* out = (float*)d_out;
    float* so  = (float*)d_ws;

    const bool use_ws = (ws_size >= (size_t)NPAIR * 2 * sizeof(float));
    // 12288 wave-tasks / 4 waves per block = 3072 blocks
    if (use_ws) {
        precomp_norm<<<(NPAIR + 255) / 256, 256, 0, stream>>>(max_, min_, so);
        dct_kernel<true><<<3072, 256, 0, stream>>>(x, yw, so, max_, min_, out);
    } else {
        dct_kernel<false><<<3072, 256, 0, stream>>>(x, yw, nullptr, max_, min_, out);
    }
}

// Round 3
// 189.191 us; speedup vs baseline: 1.1896x; 1.1896x over previous
//
#include <hip/hip_runtime.h>

// DCT_18769007084406: RGB->YCbCr (1x1 conv) -> 8x8 stride-8 block DCT
// (grouped conv) -> 32x repeated (t-min)/d normalization (closed form).
//
// R5: in-wave row-split. R4's u-split doubled wave parallelism but also
// doubled HBM fetch (61->108 MB): 6 wave-tasks/band each re-read R/G/B.
// Now one wave-task = (band, channel, column-half). Lanes 0-31 cover
// block-cols 0-31 rows 0-3; lanes 32-63 same blocks, rows 4-7. Each lane
// loads only its 4 rows (24 float4 loads), row-DCTs them, and the two
// row-halves are combined IN-WAVE via __shfl_xor(z, 32) -- no LDS, no
// extra global traffic. Lane keeps a 4x8 accumulator (u-half == its
// row-half), so per-wave serial work halves while read redundancy stays
// at R3's 3x (the 3 channel-waves of a half-band share a workgroup ->
// L1 dedup). rh-dependent basis coeffs are (rh ? constA : constB) with
// compile-time indices -> v_cndmask between literals, no scratch table.
// Normal stores (R4's nt stores grew WRITE_SIZE 7%).

#define HW 512
#define CHST (HW * HW)       // channel stride in x
#define NPAIR 6144           // 32 * 192 (b, out-channel) pairs
#define EPS 1e-6f

// basis[u][i] = c(u) * cos(pi*u*(i+0.5)/8); c(0)=sqrt(1/8), c(u>0)=0.5
static constexpr float BASIS[8][8] = {
  { 0.35355339059327373f, 0.35355339059327373f, 0.35355339059327373f, 0.35355339059327373f,
    0.35355339059327373f, 0.35355339059327373f, 0.35355339059327373f, 0.35355339059327373f },
  { 0.49039264020161522f, 0.41573480615127262f, 0.27778511650980114f, 0.09754516100806412f,
   -0.09754516100806412f,-0.27778511650980114f,-0.41573480615127262f,-0.49039264020161522f },
  { 0.46193976625564337f, 0.19134171618254492f,-0.19134171618254492f,-0.46193976625564337f,
   -0.46193976625564337f,-0.19134171618254492f, 0.19134171618254492f, 0.46193976625564337f },
  { 0.41573480615127262f,-0.09754516100806412f,-0.49039264020161522f,-0.27778511650980114f,
    0.27778511650980114f, 0.49039264020161522f, 0.09754516100806412f,-0.41573480615127262f },
  { 0.35355339059327373f,-0.35355339059327373f,-0.35355339059327373f, 0.35355339059327373f,
    0.35355339059327373f,-0.35355339059327373f,-0.35355339059327373f, 0.35355339059327373f },
  { 0.27778511650980114f,-0.49039264020161522f, 0.09754516100806412f, 0.41573480615127262f,
   -0.41573480615127262f,-0.09754516100806412f, 0.49039264020161522f,-0.27778511650980114f },
  { 0.19134171618254492f,-0.46193976625564337f, 0.46193976625564337f,-0.19134171618254492f,
   -0.19134171618254492f, 0.46193976625564337f,-0.46193976625564337f, 0.19134171618254492f },
  { 0.09754516100806412f,-0.27778511650980114f, 0.41573480615127262f,-0.49039264020161522f,
    0.49039264020161522f,-0.41573480615127262f, 0.27778511650980114f,-0.09754516100806412f }
};

// t_32 = a^32 * t0 - min * sum_{k=1..32} a^k, a = 1/(max-min+eps)
__global__ void precomp_norm(const float* __restrict__ max_,
                             const float* __restrict__ min_,
                             float* __restrict__ so) {
    int i = blockIdx.x * 256 + threadIdx.x;
    if (i >= NPAIR) return;
    float mn = min_[i], mx = max_[i];
    float d = mx - mn + EPS;
    float a = 1.0f / d;
    float a2 = a * a, a4 = a2 * a2, a8 = a4 * a4, a16 = a8 * a8, a32 = a16 * a16;
    float geo = a * (1.0f - a32) / (1.0f - a);   // sum_{k=1..32} a^k
    so[2 * i]     = a32;
    so[2 * i + 1] = -mn * geo;
}

template <bool USE_WS>
__global__ __launch_bounds__(256, 4)
void dct_kernel(const float* __restrict__ x,
                const float* __restrict__ ycbcr_w,
                const float* __restrict__ so,
                const float* __restrict__ max_,
                const float* __restrict__ min_,
                float* __restrict__ out) {
    // wave-task: band*6 + half*3 + c  (12288 total; the 3 channel-waves of
    // one half-band are consecutive -> same workgroup -> L1 share)
    const int wt   = blockIdx.x * 4 + (threadIdx.x >> 6);
    const int lane = threadIdx.x & 63;
    const int rh   = lane >> 5;            // row-half: rows rh*4 .. rh*4+3
    const int lx   = lane & 31;            // block-col within the half

    const int band = wt / 6;               // (b, by)
    const int rem  = wt - band * 6;
    const int half = (rem >= 3) ? 1 : 0;   // column half of the band
    const int c    = rem - half * 3;       // YCbCr channel
    const int by   = band & 63;
    const int b    = band >> 6;
    const int bx   = half * 32 + lx;       // this lane's 8x8 block column

    // channel weights (wave-uniform)
    const float wr = ycbcr_w[3 * c];
    const float wg = ycbcr_w[3 * c + 1];
    const float wb = ycbcr_w[3 * c + 2];

    // lane's 4 rows start here
    const float* base = x + (size_t)(b * 3) * CHST
                          + (size_t)(by * 8 + rh * 4) * HW + bx * 8;

    float acc[4][8];   // acc[u0][v] for u = rh*4 + u0
#pragma unroll
    for (int u0 = 0; u0 < 4; ++u0)
#pragma unroll
        for (int v = 0; v < 8; ++v) acc[u0][v] = 0.0f;

#pragma unroll
    for (int t = 0; t < 4; ++t) {
        const float* rp = base + t * HW;
        float4 r0 = *(const float4*)(rp);
        float4 r1 = *(const float4*)(rp + 4);
        float4 g0 = *(const float4*)(rp + CHST);
        float4 g1 = *(const float4*)(rp + CHST + 4);
        float4 b0 = *(const float4*)(rp + 2 * CHST);
        float4 b1 = *(const float4*)(rp + 2 * CHST + 4);

        float y[8];
        y[0] = fmaf(wr, r0.x, fmaf(wg, g0.x, wb * b0.x));
        y[1] = fmaf(wr, r0.y, fmaf(wg, g0.y, wb * b0.y));
        y[2] = fmaf(wr, r0.z, fmaf(wg, g0.z, wb * b0.z));
        y[3] = fmaf(wr, r0.w, fmaf(wg, g0.w, wb * b0.w));
        y[4] = fmaf(wr, r1.x, fmaf(wg, g1.x, wb * b1.x));
        y[5] = fmaf(wr, r1.y, fmaf(wg, g1.y, wb * b1.y));
        y[6] = fmaf(wr, r1.z, fmaf(wg, g1.z, wb * b1.z));
        y[7] = fmaf(wr, r1.w, fmaf(wg, g1.w, wb * b1.w));

        // row DCT: z[v] = sum_j basis[v][j] * y[j]
        float z[8];
#pragma unroll
        for (int v = 0; v < 8; ++v) {
            float zz = y[0] * BASIS[v][0];
#pragma unroll
            for (int j = 1; j < 8; ++j)
                zz = fmaf(y[j], BASIS[v][j], zz);
            z[v] = zz;
        }

        // partner row-half's z for the same block (lane ^ 32)
        float pz[8];
#pragma unroll
        for (int v = 0; v < 8; ++v)
            pz[v] = __shfl_xor(z[v], 32, 64);

        // column accumulate: own row gi = rh*4+t, partner row (1-rh)*4+t.
        // Compile-time indices, runtime rh -> v_cndmask between literals.
#pragma unroll
        for (int u0 = 0; u0 < 4; ++u0) {
            const float bo = rh ? BASIS[4 + u0][4 + t] : BASIS[u0][t];
            const float bp = rh ? BASIS[4 + u0][t]     : BASIS[u0][4 + t];
#pragma unroll
            for (int v = 0; v < 8; ++v)
                acc[u0][v] = fmaf(bo, z[v], fmaf(bp, pz[v], acc[u0][v]));
        }
    }

    const int obase = b * 192 + c * 64;    // first output channel index
    const int uh    = rh * 4;              // lane stores its u-half
    float* op = out + ((size_t)obase * 64 + by) * 64 + bx;
    const float2* sop = (const float2*)so + obase;   // (scale, offset) pairs

#pragma unroll
    for (int u0 = 0; u0 < 4; ++u0) {
#pragma unroll
        for (int v = 0; v < 8; ++v) {
            const int k = (uh + u0) * 8 + v;
            float s, o;
            if (USE_WS) {
                float2 p = sop[k];                 // L1-hit small table
                s = p.x;
                o = p.y;
            } else {
                float mn = min_[obase + k], mx = max_[obase + k];
                float d  = mx - mn + EPS;
                float a  = 1.0f / d;
                float a2 = a * a, a4 = a2 * a2, a8 = a4 * a4, a16 = a8 * a8, a32 = a16 * a16;
                s = a32;
                o = -mn * (a * (1.0f - a32) / (1.0f - a));
            }
            op[(size_t)k * 4096] = fmaf(s, acc[u0][v], o);
        }
    }
}

extern "C" void kernel_launch(void* const* d_in, const int* in_sizes, int n_in,
                              void* d_out, int out_size, void* d_ws, size_t ws_size,
                              hipStream_t stream) {
    const float* x    = (const float*)d_in[0];
    const float* max_ = (const float*)d_in[1];
    const float* min_ = (const float*)d_in[2];
    const float* yw   = (const float*)d_in[3];
    float* out = (float*)d_out;
    float* so  = (float*)d_ws;

    const bool use_ws = (ws_size >= (size_t)NPAIR * 2 * sizeof(float));
    // 12288 wave-tasks / 4 waves per 256-thread block = 3072 blocks
    if (use_ws) {
        precomp_norm<<<(NPAIR + 255) / 256, 256, 0, stream>>>(max_, min_, so);
        dct_kernel<true><<<3072, 256, 0, stream>>>(x, yw, so, max_, min_, out);
    } else {
        dct_kernel<false><<<3072, 256, 0, stream>>>(x, yw, nullptr, max_, min_, out);
    }
}